// Round 10
// baseline (242.724 us; speedup 1.0000x reference)
//
#include <hip/hip_runtime.h>
#include <hip/hip_bf16.h>

typedef __hip_bfloat16 bf16;
typedef __attribute__((ext_vector_type(8))) short short8v;          // 8 bf16 (4 VGPRs)
typedef __attribute__((ext_vector_type(8))) unsigned short ushort8v;
typedef __attribute__((ext_vector_type(4))) unsigned short ushort4v;
typedef __attribute__((ext_vector_type(4))) float float4v;

__device__ __forceinline__ float bfu2f(unsigned short u) {
    union { unsigned int i; float f; } v; v.i = ((unsigned int)u) << 16; return v.f;
}
__device__ __forceinline__ unsigned short f2bfu_rn(float x) {
    union { float f; unsigned int i; } u; u.f = x;
    unsigned int r = (u.i + 0x7FFFu + ((u.i >> 16) & 1u)) >> 16;
    return (unsigned short)r;
}

// ---------- cast+transpose weights: W[k][n] fp32 -> Wt[n][k] bf16. grid (4,4,4) ----------
__global__ __launch_bounds__(256) void cast_wt(
    const float* __restrict__ Wq, const float* __restrict__ Wk,
    const float* __restrict__ Wv, const float* __restrict__ Wp,
    unsigned short* __restrict__ wt)
{
    __shared__ unsigned short tile[64][72];
    const float* W = (blockIdx.z == 0) ? Wq : (blockIdx.z == 1) ? Wk
                   : (blockIdx.z == 2) ? Wv : Wp;
    unsigned short* WT = wt + (size_t)blockIdx.z * 65536;
    const int t = threadIdx.x;
    const int k0 = blockIdx.x * 64, n0 = blockIdx.y * 64;
    {
        const int r = t >> 2, cseg = (t & 3) * 16;
        const float* src = W + (size_t)(k0 + r) * 256 + n0 + cseg;
        #pragma unroll
        for (int j = 0; j < 16; ++j) tile[r][cseg + j] = f2bfu_rn(src[j]);
    }
    __syncthreads();
    {
        const int ch = t & 63, lq = t >> 6;
        ushort8v o0, o1;
        #pragma unroll
        for (int i = 0; i < 8; ++i) o0[i] = tile[lq * 16 + i][ch];
        #pragma unroll
        for (int i = 0; i < 8; ++i) o1[i] = tile[lq * 16 + 8 + i][ch];
        unsigned short* dst = WT + (size_t)(n0 + ch) * 256 + k0 + lq * 16;
        *(ushort8v*)(dst)     = o0;
        *(ushort8v*)(dst + 8) = o1;
    }
}

// ---------- MFMA projection core: 16 m-rows x 128 n-cols per wave ----------
__device__ __forceinline__ void proj_core(
    const float* __restrict__ aptr, const unsigned short* __restrict__ Wt,
    int nc0, int m16, int quad, float4v acc[8])
{
    #pragma unroll
    for (int i = 0; i < 8; ++i) acc[i] = (float4v){0.f, 0.f, 0.f, 0.f};
    #pragma unroll
    for (int ks = 0; ks < 8; ++ks) {
        float4 a0 = *(const float4*)(aptr + ks * 32);
        float4 a1 = *(const float4*)(aptr + ks * 32 + 4);
        short8v af;
        af[0] = (short)f2bfu_rn(a0.x); af[1] = (short)f2bfu_rn(a0.y);
        af[2] = (short)f2bfu_rn(a0.z); af[3] = (short)f2bfu_rn(a0.w);
        af[4] = (short)f2bfu_rn(a1.x); af[5] = (short)f2bfu_rn(a1.y);
        af[6] = (short)f2bfu_rn(a1.z); af[7] = (short)f2bfu_rn(a1.w);
        #pragma unroll
        for (int i = 0; i < 8; ++i) {
            short8v bfr = *(const short8v*)(Wt + (size_t)(nc0 + i * 16 + m16) * 256 + ks * 32 + quad * 8);
            acc[i] = __builtin_amdgcn_mfma_f32_16x16x32_bf16(af, bfr, acc[i], 0, 0, 0);
        }
    }
}

// ---------- fused q/k/v projections. grid 691: [0,19) q, [19,355) k, [355,691) v ----------
__global__ __launch_bounds__(256) void proj_all(
    const float* __restrict__ q, const float* __restrict__ k, const float* __restrict__ v,
    const unsigned short* __restrict__ wt,
    unsigned short* __restrict__ qb, unsigned short* __restrict__ kb,
    unsigned short* __restrict__ vt)
{
    const int t = threadIdx.x;
    const int wave = t >> 6, lane = t & 63;
    const int m16 = lane & 15, quad = lane >> 4;
    const int msub = (wave & 1) * 16;
    const int nc0 = (wave >> 1) * 128;
    const int bx = blockIdx.x;

    float4v acc[8];
    if (bx < 19) {                       // ---- query -> qb (row-major), M=600
        const int m0 = bx * 32;
        const int arow = min(m0 + msub + m16, 599);
        proj_core(q + (size_t)arow * 256 + quad * 8, wt, nc0, m16, quad, acc);
        #pragma unroll
        for (int i = 0; i < 8; ++i)
            #pragma unroll
            for (int r = 0; r < 4; ++r) {
                int m = m0 + msub + quad * 4 + r;
                if (m < 600)
                    qb[(size_t)m * 256 + nc0 + i * 16 + m16] = f2bfu_rn(acc[i][r]);
            }
    } else if (bx < 355) {               // ---- key -> kb (row-major), M=10752
        const int m0 = (bx - 19) * 32;
        proj_core(k + (size_t)(m0 + msub + m16) * 256 + quad * 8, wt + 65536, nc0, m16, quad, acc);
        #pragma unroll
        for (int i = 0; i < 8; ++i)
            #pragma unroll
            for (int r = 0; r < 4; ++r) {
                int m = m0 + msub + quad * 4 + r;
                kb[(size_t)m * 256 + nc0 + i * 16 + m16] = f2bfu_rn(acc[i][r]);
            }
    } else {                             // ---- value -> vt (transposed), M=10752
        const int m0 = (bx - 355) * 32;
        proj_core(v + (size_t)(m0 + msub + m16) * 256 + quad * 8, wt + 131072, nc0, m16, quad, acc);
        const int bb = (m0 >= 5376) ? 1 : 0;
        const int lcol = m0 - bb * 5376 + msub + quad * 4;
        #pragma unroll
        for (int i = 0; i < 8; ++i) {
            const int ch = nc0 + i * 16 + m16;
            ushort4v p;
            #pragma unroll
            for (int r = 0; r < 4; ++r) p[r] = f2bfu_rn(acc[i][r]);
            *(ushort4v*)(vt + (size_t)(bb * 256 + ch) * 5376 + lcol) = p;
        }
    }
}

// ---------- output projection: x = xb @ Wp + bp, fp32 out. grid 19 ----------
__global__ __launch_bounds__(256) void proj_out(
    const float* __restrict__ xb, const unsigned short* __restrict__ Wtp,
    const float* __restrict__ bp, float* __restrict__ out)
{
    const int t = threadIdx.x;
    const int wave = t >> 6, lane = t & 63;
    const int m16 = lane & 15, quad = lane >> 4;
    const int msub = (wave & 1) * 16;
    const int nc0 = (wave >> 1) * 128;
    const int m0 = blockIdx.x * 32;

    const int arow = min(m0 + msub + m16, 599);
    float4v acc[8];
    proj_core(xb + (size_t)arow * 256 + quad * 8, Wtp, nc0, m16, quad, acc);

    #pragma unroll
    for (int i = 0; i < 8; ++i) {
        const float bv = bp[nc0 + i * 16 + m16];
        #pragma unroll
        for (int r = 0; r < 4; ++r) {
            int m = m0 + msub + quad * 4 + r;
            if (m < 600)
                out[(size_t)m * 256 + nc0 + i * 16 + m16] = acc[i][r] + bv;
        }
    }
}

// ---------- fused QK + softmax + PV. grid (19,16), 512 thr (8 waves) ----------
// Wave w owns l-range [w*672,(w+1)*672), split in 3 chunks of 224.
// QK computes P^T (A=k, B=q) so each lane holds 4 consecutive-l logits -> ds_write_b64
// into wave-private LDS [n][l]; flush logits to global attn (for mask); PV reads
// A-frags back with exp applied. Single attn HBM write, zero attn HBM read here.
__global__ __launch_bounds__(512) void attn_fused(
    const unsigned short* __restrict__ qb, const unsigned short* __restrict__ kb,
    const unsigned short* __restrict__ vt,
    unsigned short* __restrict__ attn, float* __restrict__ xb)
{
    __shared__ unsigned short probs[8][16 * 232];   // 59,392 B (232 = 224 + 8 pad)
    __shared__ float partial[8][64][9];             // 18,432 B
    __shared__ float SrowP[8][16];

    const int t = threadIdx.x;
    const int wave = t >> 6, lane = t & 63;
    const int n0 = blockIdx.x * 16;
    const int bh = blockIdx.y;
    const int b = bh >> 3, h = bh & 7;
    const int m16 = lane & 15, quad = lane >> 4;
    const float scale = 0.17677669529663687f;   // 1/sqrt(32)

    // q B-frag: B[k=quad*8+j][n=m16]
    const unsigned short* qp = qb + (size_t)(b * 300 + min(n0 + m16, 299)) * 256 + h * 32 + quad * 8;
    const short8v qfrag = *(const short8v*)qp;

    const unsigned short* kbase = kb + (size_t)(b * 5376) * 256 + h * 32 + quad * 8;
    const unsigned short* vt0 = vt + (size_t)(b * 256 + h * 32 + m16) * 5376;
    const unsigned short* vt1 = vt0 + (size_t)16 * 5376;

    unsigned short* pw = &probs[wave][0];
    const int lwave = wave * 672;

    float4v c0 = {0.f, 0.f, 0.f, 0.f};
    float4v c1 = {0.f, 0.f, 0.f, 0.f};
    float sm = 0.f;

    for (int cch = 0; cch < 3; ++cch) {
        const int lc = lwave + cch * 224;

        // ---- QK: 14 tiles of 16 l. A = k (m=l), B = q (n=n). C: row=l, col=n.
        for (int i = 0; i < 14; ++i) {
            const int lcol = lc + i * 16 + m16;
            short8v kf = *(const short8v*)(kbase + (size_t)lcol * 256);
            float4v c = {0.f, 0.f, 0.f, 0.f};
            c = __builtin_amdgcn_mfma_f32_16x16x32_bf16(kf, qfrag, c, 0, 0, 0);
            // lane holds n=m16, l = i*16 + quad*4 + r  (4 consecutive l)
            ushort4v pk;
            #pragma unroll
            for (int r = 0; r < 4; ++r) pk[r] = f2bfu_rn(c[r] * scale);
            *(ushort4v*)(pw + m16 * 232 + i * 16 + quad * 4) = pk;
        }

        // ---- flush logits to global attn (coalesced-ish, 64B segments per row)
        {
            const int row = lane >> 2;
            const int n = n0 + row;
            if (n < 300) {
                unsigned short* gdst = attn + ((size_t)(b * 300 + n) * 8 + h) * 5376 + lc;
                const unsigned short* lsrc = pw + row * 232;
                #pragma unroll
                for (int it = 0; it < 7; ++it) {
                    const int colk = (lane & 3) * 8 + it * 32;
                    *(ushort8v*)(gdst + colk) = *(const ushort8v*)(lsrc + colk);
                }
            }
        }

        // ---- PV: 7 K-steps of 32 l. A[m=n=m16][k=l], exp on read.
        for (int step = 0; step < 7; ++step) {
            const int lloc = step * 32 + quad * 8;
            ushort8v ua = *(const ushort8v*)(pw + m16 * 232 + lloc);
            short8v af;
            #pragma unroll
            for (int j = 0; j < 8; ++j) {
                float e = __expf(bfu2f(ua[j]));
                sm += e;
                af[j] = (short)f2bfu_rn(e);
            }
            const int lg = lc + lloc;
            short8v b0 = *(const short8v*)(vt0 + lg);
            short8v b1 = *(const short8v*)(vt1 + lg);
            c0 = __builtin_amdgcn_mfma_f32_16x16x32_bf16(af, b0, c0, 0, 0, 0);
            c1 = __builtin_amdgcn_mfma_f32_16x16x32_bf16(af, b1, c1, 0, 0, 0);
        }
    }

    // sm currently per-lane over (rows quad*4..+3?? no: PV lane covers row n=m16, l-subset)
    // reduce over the 4 quads sharing the same n (lanes differ in bits 4,5)
    sm += __shfl_xor(sm, 16);
    sm += __shfl_xor(sm, 32);
    if (lane < 16) SrowP[wave][lane] = sm;
    #pragma unroll
    for (int j = 0; j < 4; ++j) {
        partial[wave][lane][j]     = c0[j];
        partial[wave][lane][4 + j] = c1[j];
    }
    __syncthreads();

    if (t < 64) {
        float acc[8] = {0.f, 0.f, 0.f, 0.f, 0.f, 0.f, 0.f, 0.f};
        #pragma unroll
        for (int w = 0; w < 8; ++w)
            #pragma unroll
            for (int j = 0; j < 8; ++j) acc[j] += partial[w][t][j];

        const int d = t & 15, q = t >> 4;
        #pragma unroll
        for (int r = 0; r < 4; ++r) {
            const int row = q * 4 + r;
            const int nn = n0 + row;
            if (nn < 300) {
                float S = 0.f;
                #pragma unroll
                for (int w = 0; w < 8; ++w) S += SrowP[w][row];
                float* o = xb + (size_t)(b * 300 + nn) * 256 + h * 32 + d;
                o[0]  = acc[r] / S;
                o[16] = acc[4 + r] / S;
            }
        }
    }
}

// ---------- mask branch: folded scalar fields + 8-pixel vector loads. grid (600,4) ----------
__global__ __launch_bounds__(256) void mask_kernel(
    const bf16* __restrict__ attn,
    const float* __restrict__ W1, const float* __restrict__ b1,
    const float* __restrict__ W2, const float* __restrict__ b2,
    const float* __restrict__ W3, const float* __restrict__ b3,
    const float* __restrict__ Wm, const float* __restrict__ bmp,
    float* __restrict__ out)
{
    __shared__ float g2s[1024];
    __shared__ float g3s[256];
    __shared__ float w1s[64], w2s[64], w3s[64];
    __shared__ float b1s[8], b2s[8], b3s[8];
    __shared__ float wms[24];
    __shared__ float bms;

    const int t  = threadIdx.x;
    const int bn = blockIdx.x;
    const int ph = blockIdx.y;             // pixel quarter: 0..3
    const unsigned short* ap = (const unsigned short*)attn + (size_t)bn * 8 * 5376;

    if (t < 64) { w1s[t] = W1[t]; w2s[t] = W2[t]; w3s[t] = W3[t]; }
    if (t < 8)  { b1s[t] = b1[t]; b2s[t] = b2[t]; b3s[t] = b3[t]; }
    if (t < 24) wms[t] = Wm[t];
    if (t == 0) bms = bmp[0];
    __syncthreads();

    for (int l2 = t * 4; l2 < 1024; l2 += 1024) {
        ushort8v u[8];
        #pragma unroll
        for (int hh = 0; hh < 8; ++hh)
            u[hh] = *(const ushort8v*)(ap + hh * 5376 + 4096 + l2);
        #pragma unroll
        for (int pp = 0; pp < 4; ++pp) {
            float g = 0.f;
            #pragma unroll
            for (int hh = 0; hh < 8; ++hh) {
                float s = b2s[hh];
                #pragma unroll
                for (int hp = 0; hp < 8; ++hp) s += bfu2f(u[hp][pp]) * w2s[hp * 8 + hh];
                g += fmaxf(s, 0.f) * wms[8 + hh];
            }
            g2s[l2 + pp] = g;
        }
    }
    if (t < 64) {
        int l3 = t * 4;
        ushort8v u[8];
        #pragma unroll
        for (int hh = 0; hh < 8; ++hh)
            u[hh] = *(const ushort8v*)(ap + hh * 5376 + 5120 + l3);
        #pragma unroll
        for (int pp = 0; pp < 4; ++pp) {
            float g = 0.f;
            #pragma unroll
            for (int hh = 0; hh < 8; ++hh) {
                float s = b3s[hh];
                #pragma unroll
                for (int hp = 0; hp < 8; ++hp) s += bfu2f(u[hp][pp]) * w3s[hp * 8 + hh];
                g += fmaxf(s, 0.f) * wms[16 + hh];
            }
            g3s[l3 + pp] = g;
        }
    }
    __syncthreads();

    if (t < 128) {
        const int p0 = ph * 1024 + t * 8;
        ushort8v u[8];
        #pragma unroll
        for (int hh = 0; hh < 8; ++hh)
            u[hh] = *(const ushort8v*)(ap + hh * 5376 + p0);

        float res[8];
        #pragma unroll
        for (int pp = 0; pp < 8; ++pp) {
            const int p = p0 + pp;
            const int Y = p >> 6, X = p & 63;

            float acc = bms;
            #pragma unroll
            for (int hh = 0; hh < 8; ++hh) {
                float s = b1s[hh];
                #pragma unroll
                for (int hp = 0; hp < 8; ++hp) s += bfu2f(u[hp][pp]) * w1s[hp * 8 + hh];
                acc += fmaxf(s, 0.f) * wms[hh];
            }
            {
                float ry = fminf(fmaxf(0.5f * Y - 0.25f, 0.f), 31.f);
                float rx = fminf(fmaxf(0.5f * X - 0.25f, 0.f), 31.f);
                int y0 = (int)ry, x0 = (int)rx;
                int y1 = min(y0 + 1, 31), x1 = min(x0 + 1, 31);
                float wy = ry - (float)y0, wx = rx - (float)x0;
                acc += (g2s[y0 * 32 + x0] * (1.f - wx) + g2s[y0 * 32 + x1] * wx) * (1.f - wy)
                     + (g2s[y1 * 32 + x0] * (1.f - wx) + g2s[y1 * 32 + x1] * wx) * wy;
            }
            {
                float ry = fminf(fmaxf(0.25f * Y - 0.375f, 0.f), 15.f);
                float rx = fminf(fmaxf(0.25f * X - 0.375f, 0.f), 15.f);
                int y0 = (int)ry, x0 = (int)rx;
                int y1 = min(y0 + 1, 15), x1 = min(x0 + 1, 15);
                float wy = ry - (float)y0, wx = rx - (float)x0;
                acc += (g3s[y0 * 16 + x0] * (1.f - wx) + g3s[y0 * 16 + x1] * wx) * (1.f - wy)
                     + (g3s[y1 * 16 + x0] * (1.f - wx) + g3s[y1 * 16 + x1] * wx) * wy;
            }
            res[pp] = fmaxf(acc, 0.f);
        }
        float* o = out + 153600 + (size_t)bn * 4096 + p0;
        #pragma unroll
        for (int pp = 0; pp < 8; ++pp) o[pp] = res[pp];
    }
}

// ---------- launch ----------
extern "C" void kernel_launch(void* const* d_in, const int* in_sizes, int n_in,
                              void* d_out, int out_size, void* d_ws, size_t ws_size,
                              hipStream_t stream) {
    const float* query = (const float*)d_in[0];
    const float* key   = (const float*)d_in[1];
    const float* value = (const float*)d_in[2];
    const float* Wq = (const float*)d_in[5];
    const float* Wk = (const float*)d_in[6];
    const float* Wv = (const float*)d_in[7];
    const float* Wp = (const float*)d_in[8];
    const float* bp = (const float*)d_in[9];
    const float* W1 = (const float*)d_in[10];
    const float* b1 = (const float*)d_in[11];
    const float* W2 = (const float*)d_in[12];
    const float* b2 = (const float*)d_in[13];
    const float* W3 = (const float*)d_in[14];
    const float* b3 = (const float*)d_in[15];
    const float* Wm = (const float*)d_in[16];
    const float* bm = (const float*)d_in[17];
    float* out = (float*)d_out;

    char* ws = (char*)d_ws;
    unsigned short* wt = (unsigned short*)(ws);       // 4*65536 bf16 = 524,288 B
    bf16*  qb   = (bf16*) (ws + 524288);              // 600*256 bf16
    bf16*  kb   = (bf16*) (ws + 831488);              // 10752*256 bf16
    bf16*  vt   = (bf16*) (ws + 6336512);             // 512*5376 bf16
    bf16*  attn = (bf16*) (ws + 11841536);            // 600*8*5376 bf16
    float* xb   = (float*)(ws + 63451136);            // 600*256 fp32

    cast_wt<<<dim3(4, 4, 4), 256, 0, stream>>>(Wq, Wk, Wv, Wp, wt);

    proj_all<<<691, 256, 0, stream>>>(query, key, value, wt,
        (unsigned short*)qb, (unsigned short*)kb, (unsigned short*)vt);

    attn_fused<<<dim3(19, 16), 512, 0, stream>>>(
        (const unsigned short*)qb, (const unsigned short*)kb, (const unsigned short*)vt,
        (unsigned short*)attn, xb);

    mask_kernel<<<dim3(600, 4), 256, 0, stream>>>(attn, W1, b1, W2, b2, W3, b3, Wm, bm, out);

    proj_out<<<19, 256, 0, stream>>>(xb, (const unsigned short*)wt + 196608, bp, out);
}

// Round 11
// 218.791 us; speedup vs baseline: 1.1094x; 1.1094x over previous
//
#include <hip/hip_runtime.h>
#include <hip/hip_bf16.h>

typedef __hip_bfloat16 bf16;
typedef __attribute__((ext_vector_type(8))) short short8v;          // 8 bf16 (4 VGPRs)
typedef __attribute__((ext_vector_type(8))) unsigned short ushort8v;
typedef __attribute__((ext_vector_type(4))) unsigned short ushort4v;
typedef __attribute__((ext_vector_type(4))) float float4v;

__device__ __forceinline__ float bfu2f(unsigned short u) {
    union { unsigned int i; float f; } v; v.i = ((unsigned int)u) << 16; return v.f;
}
__device__ __forceinline__ unsigned short f2bfu_rn(float x) {
    union { float f; unsigned int i; } u; u.f = x;
    unsigned int r = (u.i + 0x7FFFu + ((u.i >> 16) & 1u)) >> 16;
    return (unsigned short)r;
}

// ---------- cast+transpose weights: W[k][n] fp32 -> Wt[n][k] bf16. grid (4,4,4) ----------
__global__ __launch_bounds__(256) void cast_wt(
    const float* __restrict__ Wq, const float* __restrict__ Wk,
    const float* __restrict__ Wv, const float* __restrict__ Wp,
    unsigned short* __restrict__ wt)
{
    __shared__ unsigned short tile[64][72];
    const float* W = (blockIdx.z == 0) ? Wq : (blockIdx.z == 1) ? Wk
                   : (blockIdx.z == 2) ? Wv : Wp;
    unsigned short* WT = wt + (size_t)blockIdx.z * 65536;
    const int t = threadIdx.x;
    const int k0 = blockIdx.x * 64, n0 = blockIdx.y * 64;
    {
        const int r = t >> 2, cseg = (t & 3) * 16;
        const float* src = W + (size_t)(k0 + r) * 256 + n0 + cseg;
        #pragma unroll
        for (int j = 0; j < 16; ++j) tile[r][cseg + j] = f2bfu_rn(src[j]);
    }
    __syncthreads();
    {
        const int ch = t & 63, lq = t >> 6;
        ushort8v o0, o1;
        #pragma unroll
        for (int i = 0; i < 8; ++i) o0[i] = tile[lq * 16 + i][ch];
        #pragma unroll
        for (int i = 0; i < 8; ++i) o1[i] = tile[lq * 16 + 8 + i][ch];
        unsigned short* dst = WT + (size_t)(n0 + ch) * 256 + k0 + lq * 16;
        *(ushort8v*)(dst)     = o0;
        *(ushort8v*)(dst + 8) = o1;
    }
}

// ---------- MFMA projection core: 16 m-rows x 128 n-cols per wave ----------
__device__ __forceinline__ void proj_core(
    const float* __restrict__ aptr, const unsigned short* __restrict__ Wt,
    int nc0, int m16, int quad, float4v acc[8])
{
    #pragma unroll
    for (int i = 0; i < 8; ++i) acc[i] = (float4v){0.f, 0.f, 0.f, 0.f};
    #pragma unroll
    for (int ks = 0; ks < 8; ++ks) {
        float4 a0 = *(const float4*)(aptr + ks * 32);
        float4 a1 = *(const float4*)(aptr + ks * 32 + 4);
        short8v af;
        af[0] = (short)f2bfu_rn(a0.x); af[1] = (short)f2bfu_rn(a0.y);
        af[2] = (short)f2bfu_rn(a0.z); af[3] = (short)f2bfu_rn(a0.w);
        af[4] = (short)f2bfu_rn(a1.x); af[5] = (short)f2bfu_rn(a1.y);
        af[6] = (short)f2bfu_rn(a1.z); af[7] = (short)f2bfu_rn(a1.w);
        #pragma unroll
        for (int i = 0; i < 8; ++i) {
            short8v bfr = *(const short8v*)(Wt + (size_t)(nc0 + i * 16 + m16) * 256 + ks * 32 + quad * 8);
            acc[i] = __builtin_amdgcn_mfma_f32_16x16x32_bf16(af, bfr, acc[i], 0, 0, 0);
        }
    }
}

// ---------- fused q/k/v projections. grid 691: [0,19) q, [19,355) k, [355,691) v ----------
__global__ __launch_bounds__(256) void proj_all(
    const float* __restrict__ q, const float* __restrict__ k, const float* __restrict__ v,
    const unsigned short* __restrict__ wt,
    unsigned short* __restrict__ qb, unsigned short* __restrict__ kb,
    unsigned short* __restrict__ vt)
{
    const int t = threadIdx.x;
    const int wave = t >> 6, lane = t & 63;
    const int m16 = lane & 15, quad = lane >> 4;
    const int msub = (wave & 1) * 16;
    const int nc0 = (wave >> 1) * 128;
    const int bx = blockIdx.x;

    float4v acc[8];
    if (bx < 19) {                       // ---- query -> qb (row-major), M=600
        const int m0 = bx * 32;
        const int arow = min(m0 + msub + m16, 599);
        proj_core(q + (size_t)arow * 256 + quad * 8, wt, nc0, m16, quad, acc);
        #pragma unroll
        for (int i = 0; i < 8; ++i)
            #pragma unroll
            for (int r = 0; r < 4; ++r) {
                int m = m0 + msub + quad * 4 + r;
                if (m < 600)
                    qb[(size_t)m * 256 + nc0 + i * 16 + m16] = f2bfu_rn(acc[i][r]);
            }
    } else if (bx < 355) {               // ---- key -> kb (row-major), M=10752
        const int m0 = (bx - 19) * 32;
        proj_core(k + (size_t)(m0 + msub + m16) * 256 + quad * 8, wt + 65536, nc0, m16, quad, acc);
        #pragma unroll
        for (int i = 0; i < 8; ++i)
            #pragma unroll
            for (int r = 0; r < 4; ++r) {
                int m = m0 + msub + quad * 4 + r;
                kb[(size_t)m * 256 + nc0 + i * 16 + m16] = f2bfu_rn(acc[i][r]);
            }
    } else {                             // ---- value -> vt (transposed), M=10752
        const int m0 = (bx - 355) * 32;
        proj_core(v + (size_t)(m0 + msub + m16) * 256 + quad * 8, wt + 131072, nc0, m16, quad, acc);
        const int bb = (m0 >= 5376) ? 1 : 0;
        const int lcol = m0 - bb * 5376 + msub + quad * 4;
        #pragma unroll
        for (int i = 0; i < 8; ++i) {
            const int ch = nc0 + i * 16 + m16;
            ushort4v p;
            #pragma unroll
            for (int r = 0; r < 4; ++r) p[r] = f2bfu_rn(acc[i][r]);
            *(ushort4v*)(vt + (size_t)(bb * 256 + ch) * 5376 + lcol) = p;
        }
    }
}

// ---------- output projection: x = xb @ Wp + bp, fp32 out. grid 19 ----------
__global__ __launch_bounds__(256) void proj_out(
    const float* __restrict__ xb, const unsigned short* __restrict__ Wtp,
    const float* __restrict__ bp, float* __restrict__ out)
{
    const int t = threadIdx.x;
    const int wave = t >> 6, lane = t & 63;
    const int m16 = lane & 15, quad = lane >> 4;
    const int msub = (wave & 1) * 16;
    const int nc0 = (wave >> 1) * 128;
    const int m0 = blockIdx.x * 32;

    const int arow = min(m0 + msub + m16, 599);
    float4v acc[8];
    proj_core(xb + (size_t)arow * 256 + quad * 8, Wtp, nc0, m16, quad, acc);

    #pragma unroll
    for (int i = 0; i < 8; ++i) {
        const float bv = bp[nc0 + i * 16 + m16];
        #pragma unroll
        for (int r = 0; r < 4; ++r) {
            int m = m0 + msub + quad * 4 + r;
            if (m < 600)
                out[(size_t)m * 256 + nc0 + i * 16 + m16] = acc[i][r] + bv;
        }
    }
}

// ---------- fused QK + softmax + PV. grid (19,16), 512 thr (8 waves) ----------
__global__ __launch_bounds__(512) void attn_fused(
    const unsigned short* __restrict__ qb, const unsigned short* __restrict__ kb,
    const unsigned short* __restrict__ vt,
    unsigned short* __restrict__ attn, float* __restrict__ xb)
{
    __shared__ unsigned short probs[8][16 * 232];   // 59,392 B (232 = 224 + 8 pad)
    __shared__ float partial[8][64][9];             // 18,432 B
    __shared__ float SrowP[8][16];

    const int t = threadIdx.x;
    const int wave = t >> 6, lane = t & 63;
    const int n0 = blockIdx.x * 16;
    const int bh = blockIdx.y;
    const int b = bh >> 3, h = bh & 7;
    const int m16 = lane & 15, quad = lane >> 4;
    const float scale = 0.17677669529663687f;   // 1/sqrt(32)

    const unsigned short* qp = qb + (size_t)(b * 300 + min(n0 + m16, 299)) * 256 + h * 32 + quad * 8;
    const short8v qfrag = *(const short8v*)qp;

    const unsigned short* kbase = kb + (size_t)(b * 5376) * 256 + h * 32 + quad * 8;
    const unsigned short* vt0 = vt + (size_t)(b * 256 + h * 32 + m16) * 5376;
    const unsigned short* vt1 = vt0 + (size_t)16 * 5376;

    unsigned short* pw = &probs[wave][0];
    const int lwave = wave * 672;

    float4v c0 = {0.f, 0.f, 0.f, 0.f};
    float4v c1 = {0.f, 0.f, 0.f, 0.f};
    float sm = 0.f;

    for (int cch = 0; cch < 3; ++cch) {
        const int lc = lwave + cch * 224;

        // ---- QK: 14 tiles of 16 l. A = k (m=l), B = q (n=n). C: row=l, col=n.
        for (int i = 0; i < 14; ++i) {
            const int lcol = lc + i * 16 + m16;
            short8v kf = *(const short8v*)(kbase + (size_t)lcol * 256);
            float4v c = {0.f, 0.f, 0.f, 0.f};
            c = __builtin_amdgcn_mfma_f32_16x16x32_bf16(kf, qfrag, c, 0, 0, 0);
            ushort4v pk;
            #pragma unroll
            for (int r = 0; r < 4; ++r) pk[r] = f2bfu_rn(c[r] * scale);
            *(ushort4v*)(pw + m16 * 232 + i * 16 + quad * 4) = pk;
        }

        // ---- flush logits to global attn (for the mask kernel)
        {
            const int row = lane >> 2;
            const int n = n0 + row;
            if (n < 300) {
                unsigned short* gdst = attn + ((size_t)(b * 300 + n) * 8 + h) * 5376 + lc;
                const unsigned short* lsrc = pw + row * 232;
                #pragma unroll
                for (int it = 0; it < 7; ++it) {
                    const int colk = (lane & 3) * 8 + it * 32;
                    *(ushort8v*)(gdst + colk) = *(const ushort8v*)(lsrc + colk);
                }
            }
        }

        // ---- PV: 7 K-steps of 32 l. A[m=n=m16][k=l], exp on read.
        for (int step = 0; step < 7; ++step) {
            const int lloc = step * 32 + quad * 8;
            ushort8v ua = *(const ushort8v*)(pw + m16 * 232 + lloc);
            short8v af;
            #pragma unroll
            for (int j = 0; j < 8; ++j) {
                float e = __expf(bfu2f(ua[j]));
                sm += e;
                af[j] = (short)f2bfu_rn(e);
            }
            const int lg = lc + lloc;
            short8v b0 = *(const short8v*)(vt0 + lg);
            short8v b1 = *(const short8v*)(vt1 + lg);
            c0 = __builtin_amdgcn_mfma_f32_16x16x32_bf16(af, b0, c0, 0, 0, 0);
            c1 = __builtin_amdgcn_mfma_f32_16x16x32_bf16(af, b1, c1, 0, 0, 0);
        }
    }

    sm += __shfl_xor(sm, 16);
    sm += __shfl_xor(sm, 32);
    if (lane < 16) SrowP[wave][lane] = sm;
    #pragma unroll
    for (int j = 0; j < 4; ++j) {
        partial[wave][lane][j]     = c0[j];
        partial[wave][lane][4 + j] = c1[j];
    }
    __syncthreads();

    if (t < 64) {
        float acc[8] = {0.f, 0.f, 0.f, 0.f, 0.f, 0.f, 0.f, 0.f};
        #pragma unroll
        for (int w = 0; w < 8; ++w)
            #pragma unroll
            for (int j = 0; j < 8; ++j) acc[j] += partial[w][t][j];

        const int d = t & 15, q = t >> 4;
        #pragma unroll
        for (int r = 0; r < 4; ++r) {
            const int row = q * 4 + r;
            const int nn = n0 + row;
            if (nn < 300) {
                float S = 0.f;
                #pragma unroll
                for (int w = 0; w < 8; ++w) S += SrowP[w][row];
                float* o = xb + (size_t)(b * 300 + nn) * 256 + h * 32 + d;
                o[0]  = acc[r] / S;
                o[16] = acc[4 + r] / S;
            }
        }
    }
}

// ---------- mask branch: folded scalar fields + 8-pixel vector loads. grid (600,2) ----------
__global__ __launch_bounds__(256) void mask_kernel(
    const bf16* __restrict__ attn,
    const float* __restrict__ W1, const float* __restrict__ b1,
    const float* __restrict__ W2, const float* __restrict__ b2,
    const float* __restrict__ W3, const float* __restrict__ b3,
    const float* __restrict__ Wm, const float* __restrict__ bmp,
    float* __restrict__ out)
{
    __shared__ float g2s[1024];
    __shared__ float g3s[256];
    __shared__ float w1s[64], w2s[64], w3s[64];
    __shared__ float b1s[8], b2s[8], b3s[8];
    __shared__ float wms[24];
    __shared__ float bms;

    const int t  = threadIdx.x;
    const int bn = blockIdx.x;
    const int ph = blockIdx.y;             // pixel half: 0 or 1
    const unsigned short* ap = (const unsigned short*)attn + (size_t)bn * 8 * 5376;

    if (t < 64) { w1s[t] = W1[t]; w2s[t] = W2[t]; w3s[t] = W3[t]; }
    if (t < 8)  { b1s[t] = b1[t]; b2s[t] = b2[t]; b3s[t] = b3[t]; }
    if (t < 24) wms[t] = Wm[t];
    if (t == 0) bms = bmp[0];
    __syncthreads();

    // g2: level-2 (32x32) folded through Wm; coalesced 8B loads
    {
        const int l2 = t * 4;
        ushort4v u[8];
        #pragma unroll
        for (int hh = 0; hh < 8; ++hh)
            u[hh] = *(const ushort4v*)(ap + hh * 5376 + 4096 + l2);
        #pragma unroll
        for (int pp = 0; pp < 4; ++pp) {
            float g = 0.f;
            #pragma unroll
            for (int hh = 0; hh < 8; ++hh) {
                float s = b2s[hh];
                #pragma unroll
                for (int hp = 0; hp < 8; ++hp) s += bfu2f(u[hp][pp]) * w2s[hp * 8 + hh];
                g += fmaxf(s, 0.f) * wms[8 + hh];
            }
            g2s[l2 + pp] = g;
        }
    }
    // g3: level-3 (16x16) folded
    if (t < 64) {
        const int l3 = t * 4;
        ushort4v u[8];
        #pragma unroll
        for (int hh = 0; hh < 8; ++hh)
            u[hh] = *(const ushort4v*)(ap + hh * 5376 + 5120 + l3);
        #pragma unroll
        for (int pp = 0; pp < 4; ++pp) {
            float g = 0.f;
            #pragma unroll
            for (int hh = 0; hh < 8; ++hh) {
                float s = b3s[hh];
                #pragma unroll
                for (int hp = 0; hp < 8; ++hp) s += bfu2f(u[hp][pp]) * w3s[hp * 8 + hh];
                g += fmaxf(s, 0.f) * wms[16 + hh];
            }
            g3s[l3 + pp] = g;
        }
    }
    __syncthreads();

    {
        const int p0 = ph * 2048 + t * 8;
        ushort8v u[8];
        #pragma unroll
        for (int hh = 0; hh < 8; ++hh)
            u[hh] = *(const ushort8v*)(ap + hh * 5376 + p0);

        float res[8];
        #pragma unroll
        for (int pp = 0; pp < 8; ++pp) {
            const int p = p0 + pp;
            const int Y = p >> 6, X = p & 63;

            float acc = bms;
            #pragma unroll
            for (int hh = 0; hh < 8; ++hh) {
                float s = b1s[hh];
                #pragma unroll
                for (int hp = 0; hp < 8; ++hp) s += bfu2f(u[hp][pp]) * w1s[hp * 8 + hh];
                acc += fmaxf(s, 0.f) * wms[hh];
            }
            {
                float ry = fminf(fmaxf(0.5f * Y - 0.25f, 0.f), 31.f);
                float rx = fminf(fmaxf(0.5f * X - 0.25f, 0.f), 31.f);
                int y0 = (int)ry, x0 = (int)rx;
                int y1 = min(y0 + 1, 31), x1 = min(x0 + 1, 31);
                float wy = ry - (float)y0, wx = rx - (float)x0;
                acc += (g2s[y0 * 32 + x0] * (1.f - wx) + g2s[y0 * 32 + x1] * wx) * (1.f - wy)
                     + (g2s[y1 * 32 + x0] * (1.f - wx) + g2s[y1 * 32 + x1] * wx) * wy;
            }
            {
                float ry = fminf(fmaxf(0.25f * Y - 0.375f, 0.f), 15.f);
                float rx = fminf(fmaxf(0.25f * X - 0.375f, 0.f), 15.f);
                int y0 = (int)ry, x0 = (int)rx;
                int y1 = min(y0 + 1, 15), x1 = min(x0 + 1, 15);
                float wy = ry - (float)y0, wx = rx - (float)x0;
                acc += (g3s[y0 * 16 + x0] * (1.f - wx) + g3s[y0 * 16 + x1] * wx) * (1.f - wy)
                     + (g3s[y1 * 16 + x0] * (1.f - wx) + g3s[y1 * 16 + x1] * wx) * wy;
            }
            res[pp] = fmaxf(acc, 0.f);
        }
        float* o = out + 153600 + (size_t)bn * 4096 + p0;
        #pragma unroll
        for (int pp = 0; pp < 8; ++pp) o[pp] = res[pp];
    }
}

// ---------- launch ----------
extern "C" void kernel_launch(void* const* d_in, const int* in_sizes, int n_in,
                              void* d_out, int out_size, void* d_ws, size_t ws_size,
                              hipStream_t stream) {
    const float* query = (const float*)d_in[0];
    const float* key   = (const float*)d_in[1];
    const float* value = (const float*)d_in[2];
    const float* Wq = (const float*)d_in[5];
    const float* Wk = (const float*)d_in[6];
    const float* Wv = (const float*)d_in[7];
    const float* Wp = (const float*)d_in[8];
    const float* bp = (const float*)d_in[9];
    const float* W1 = (const float*)d_in[10];
    const float* b1 = (const float*)d_in[11];
    const float* W2 = (const float*)d_in[12];
    const float* b2 = (const float*)d_in[13];
    const float* W3 = (const float*)d_in[14];
    const float* b3 = (const float*)d_in[15];
    const float* Wm = (const float*)d_in[16];
    const float* bm = (const float*)d_in[17];
    float* out = (float*)d_out;

    char* ws = (char*)d_ws;
    unsigned short* wt = (unsigned short*)(ws);       // 4*65536 bf16 = 524,288 B
    bf16*  qb   = (bf16*) (ws + 524288);              // 600*256 bf16
    bf16*  kb   = (bf16*) (ws + 831488);              // 10752*256 bf16
    bf16*  vt   = (bf16*) (ws + 6336512);             // 512*5376 bf16
    bf16*  attn = (bf16*) (ws + 11841536);            // 600*8*5376 bf16
    float* xb   = (float*)(ws + 63451136);            // 600*256 fp32

    cast_wt<<<dim3(4, 4, 4), 256, 0, stream>>>(Wq, Wk, Wv, Wp, wt);

    proj_all<<<691, 256, 0, stream>>>(query, key, value, wt,
        (unsigned short*)qb, (unsigned short*)kb, (unsigned short*)vt);

    attn_fused<<<dim3(19, 16), 512, 0, stream>>>(
        (const unsigned short*)qb, (const unsigned short*)kb, (const unsigned short*)vt,
        (unsigned short*)attn, xb);

    mask_kernel<<<dim3(600, 2), 256, 0, stream>>>(attn, W1, b1, W2, b2, W3, b3, Wm, bm, out);

    proj_out<<<19, 256, 0, stream>>>(xb, (const unsigned short*)wt + 196608, bp, out);
}

// Round 12
// 210.523 us; speedup vs baseline: 1.1530x; 1.0393x over previous
//
#include <hip/hip_runtime.h>
#include <hip/hip_bf16.h>

typedef __hip_bfloat16 bf16;
typedef __attribute__((ext_vector_type(8))) short short8v;          // 8 bf16 (4 VGPRs)
typedef __attribute__((ext_vector_type(8))) unsigned short ushort8v;
typedef __attribute__((ext_vector_type(4))) unsigned short ushort4v;
typedef __attribute__((ext_vector_type(4))) float float4v;

__device__ __forceinline__ float bfu2f(unsigned short u) {
    union { unsigned int i; float f; } v; v.i = ((unsigned int)u) << 16; return v.f;
}
__device__ __forceinline__ unsigned short f2bfu_rn(float x) {
    union { float f; unsigned int i; } u; u.f = x;
    unsigned int r = (u.i + 0x7FFFu + ((u.i >> 16) & 1u)) >> 16;
    return (unsigned short)r;
}

// ---------- cast+transpose weights: W[k][n] fp32 -> Wt[n][k] bf16. grid (4,4,4) ----------
__global__ __launch_bounds__(256) void cast_wt(
    const float* __restrict__ Wq, const float* __restrict__ Wk,
    const float* __restrict__ Wv, const float* __restrict__ Wp,
    unsigned short* __restrict__ wt)
{
    __shared__ unsigned short tile[64][72];
    const float* W = (blockIdx.z == 0) ? Wq : (blockIdx.z == 1) ? Wk
                   : (blockIdx.z == 2) ? Wv : Wp;
    unsigned short* WT = wt + (size_t)blockIdx.z * 65536;
    const int t = threadIdx.x;
    const int k0 = blockIdx.x * 64, n0 = blockIdx.y * 64;
    {
        const int r = t >> 2, cseg = (t & 3) * 16;
        const float* src = W + (size_t)(k0 + r) * 256 + n0 + cseg;
        #pragma unroll
        for (int j = 0; j < 16; ++j) tile[r][cseg + j] = f2bfu_rn(src[j]);
    }
    __syncthreads();
    {
        const int ch = t & 63, lq = t >> 6;
        ushort8v o0, o1;
        #pragma unroll
        for (int i = 0; i < 8; ++i) o0[i] = tile[lq * 16 + i][ch];
        #pragma unroll
        for (int i = 0; i < 8; ++i) o1[i] = tile[lq * 16 + 8 + i][ch];
        unsigned short* dst = WT + (size_t)(n0 + ch) * 256 + k0 + lq * 16;
        *(ushort8v*)(dst)     = o0;
        *(ushort8v*)(dst + 8) = o1;
    }
}

// ---------- MFMA projection core: 16 m-rows x 128 n-cols per wave ----------
__device__ __forceinline__ void proj_core(
    const float* __restrict__ aptr, const unsigned short* __restrict__ Wt,
    int nc0, int m16, int quad, float4v acc[8])
{
    #pragma unroll
    for (int i = 0; i < 8; ++i) acc[i] = (float4v){0.f, 0.f, 0.f, 0.f};
    #pragma unroll
    for (int ks = 0; ks < 8; ++ks) {
        float4 a0 = *(const float4*)(aptr + ks * 32);
        float4 a1 = *(const float4*)(aptr + ks * 32 + 4);
        short8v af;
        af[0] = (short)f2bfu_rn(a0.x); af[1] = (short)f2bfu_rn(a0.y);
        af[2] = (short)f2bfu_rn(a0.z); af[3] = (short)f2bfu_rn(a0.w);
        af[4] = (short)f2bfu_rn(a1.x); af[5] = (short)f2bfu_rn(a1.y);
        af[6] = (short)f2bfu_rn(a1.z); af[7] = (short)f2bfu_rn(a1.w);
        #pragma unroll
        for (int i = 0; i < 8; ++i) {
            short8v bfr = *(const short8v*)(Wt + (size_t)(nc0 + i * 16 + m16) * 256 + ks * 32 + quad * 8);
            acc[i] = __builtin_amdgcn_mfma_f32_16x16x32_bf16(af, bfr, acc[i], 0, 0, 0);
        }
    }
}

// ---------- fused q/k/v projections. grid 691: [0,19) q, [19,355) k, [355,691) v ----------
__global__ __launch_bounds__(256) void proj_all(
    const float* __restrict__ q, const float* __restrict__ k, const float* __restrict__ v,
    const unsigned short* __restrict__ wt,
    unsigned short* __restrict__ qb, unsigned short* __restrict__ kb,
    unsigned short* __restrict__ vt)
{
    const int t = threadIdx.x;
    const int wave = t >> 6, lane = t & 63;
    const int m16 = lane & 15, quad = lane >> 4;
    const int msub = (wave & 1) * 16;
    const int nc0 = (wave >> 1) * 128;
    const int bx = blockIdx.x;

    float4v acc[8];
    if (bx < 19) {                       // ---- query -> qb (row-major), M=600
        const int m0 = bx * 32;
        const int arow = min(m0 + msub + m16, 599);
        proj_core(q + (size_t)arow * 256 + quad * 8, wt, nc0, m16, quad, acc);
        #pragma unroll
        for (int i = 0; i < 8; ++i)
            #pragma unroll
            for (int r = 0; r < 4; ++r) {
                int m = m0 + msub + quad * 4 + r;
                if (m < 600)
                    qb[(size_t)m * 256 + nc0 + i * 16 + m16] = f2bfu_rn(acc[i][r]);
            }
    } else if (bx < 355) {               // ---- key -> kb (row-major), M=10752
        const int m0 = (bx - 19) * 32;
        proj_core(k + (size_t)(m0 + msub + m16) * 256 + quad * 8, wt + 65536, nc0, m16, quad, acc);
        #pragma unroll
        for (int i = 0; i < 8; ++i)
            #pragma unroll
            for (int r = 0; r < 4; ++r) {
                int m = m0 + msub + quad * 4 + r;
                kb[(size_t)m * 256 + nc0 + i * 16 + m16] = f2bfu_rn(acc[i][r]);
            }
    } else {                             // ---- value -> vt (transposed), M=10752
        const int m0 = (bx - 355) * 32;
        proj_core(v + (size_t)(m0 + msub + m16) * 256 + quad * 8, wt + 131072, nc0, m16, quad, acc);
        const int bb = (m0 >= 5376) ? 1 : 0;
        const int lcol = m0 - bb * 5376 + msub + quad * 4;
        #pragma unroll
        for (int i = 0; i < 8; ++i) {
            const int ch = nc0 + i * 16 + m16;
            ushort4v p;
            #pragma unroll
            for (int r = 0; r < 4; ++r) p[r] = f2bfu_rn(acc[i][r]);
            *(ushort4v*)(vt + (size_t)(bb * 256 + ch) * 5376 + lcol) = p;
        }
    }
}

// ---------- fused QK + softmax + PV, l-split x3. grid (19,16,3), 512 thr ----------
// Wave w of z-block zz owns l-chunk [zz*1792 + w*224, +224).
// QK computes P^T (A=k, B=q) -> LDS [n][l] (stride 236 kills bank conflicts);
// flush logits to global attn; PV reads A-frags back with exp applied.
// Per-z partial PV sums -> xbp plane zz; per-z sum(exp) -> Sp plane zz.
__global__ __launch_bounds__(512) void attn_fused(
    const unsigned short* __restrict__ qb, const unsigned short* __restrict__ kb,
    const unsigned short* __restrict__ vt,
    unsigned short* __restrict__ attn, float* __restrict__ xbp, float* __restrict__ Sp)
{
    __shared__ unsigned short probs[8][16 * 236];   // 60,416 B
    __shared__ float partial[8][64][9];             // 18,432 B
    __shared__ float SrowP[8][16];

    const int t = threadIdx.x;
    const int wave = t >> 6, lane = t & 63;
    const int n0 = blockIdx.x * 16;
    const int bh = blockIdx.y;
    const int zz = blockIdx.z;
    const int b = bh >> 3, h = bh & 7;
    const int m16 = lane & 15, quad = lane >> 4;
    const float scale = 0.17677669529663687f;   // 1/sqrt(32)

    const unsigned short* qp = qb + (size_t)(b * 300 + min(n0 + m16, 299)) * 256 + h * 32 + quad * 8;
    const short8v qfrag = *(const short8v*)qp;

    const unsigned short* kbase = kb + (size_t)(b * 5376) * 256 + h * 32 + quad * 8;
    const unsigned short* vt0 = vt + (size_t)(b * 256 + h * 32 + m16) * 5376;
    const unsigned short* vt1 = vt0 + (size_t)16 * 5376;

    unsigned short* pw = &probs[wave][0];
    const int lc = zz * 1792 + wave * 224;

    float4v c0 = {0.f, 0.f, 0.f, 0.f};
    float4v c1 = {0.f, 0.f, 0.f, 0.f};
    float sm = 0.f;

    // ---- QK: 14 tiles of 16 l. A = k (m=l), B = q (n=n). C: row=l, col=n.
    #pragma unroll
    for (int i = 0; i < 14; ++i) {
        const int lcol = lc + i * 16 + m16;
        short8v kf = *(const short8v*)(kbase + (size_t)lcol * 256);
        float4v c = {0.f, 0.f, 0.f, 0.f};
        c = __builtin_amdgcn_mfma_f32_16x16x32_bf16(kf, qfrag, c, 0, 0, 0);
        ushort4v pk;
        #pragma unroll
        for (int r = 0; r < 4; ++r) pk[r] = f2bfu_rn(c[r] * scale);
        *(ushort4v*)(pw + m16 * 236 + i * 16 + quad * 4) = pk;
    }

    // ---- flush logits to global attn (for the mask kernel)
    {
        const int row = lane >> 2;
        const int n = n0 + row;
        if (n < 300) {
            unsigned short* gdst = attn + ((size_t)(b * 300 + n) * 8 + h) * 5376 + lc;
            const unsigned short* lsrc = pw + row * 236;
            #pragma unroll
            for (int it = 0; it < 7; ++it) {
                const int colk = (lane & 3) * 8 + it * 32;
                *(ushort8v*)(gdst + colk) = *(const ushort8v*)(lsrc + colk);
            }
        }
    }

    // ---- PV: 7 K-steps of 32 l. A[m=n=m16][k=l], exp on read.
    #pragma unroll
    for (int step = 0; step < 7; ++step) {
        const int lloc = step * 32 + quad * 8;
        ushort8v ua = *(const ushort8v*)(pw + m16 * 236 + lloc);
        short8v af;
        #pragma unroll
        for (int j = 0; j < 8; ++j) {
            float e = __expf(bfu2f(ua[j]));
            sm += e;
            af[j] = (short)f2bfu_rn(e);
        }
        const int lg = lc + lloc;
        short8v b0 = *(const short8v*)(vt0 + lg);
        short8v b1 = *(const short8v*)(vt1 + lg);
        c0 = __builtin_amdgcn_mfma_f32_16x16x32_bf16(af, b0, c0, 0, 0, 0);
        c1 = __builtin_amdgcn_mfma_f32_16x16x32_bf16(af, b1, c1, 0, 0, 0);
    }

    sm += __shfl_xor(sm, 16);
    sm += __shfl_xor(sm, 32);
    if (lane < 16) SrowP[wave][lane] = sm;
    #pragma unroll
    for (int j = 0; j < 4; ++j) {
        partial[wave][lane][j]     = c0[j];
        partial[wave][lane][4 + j] = c1[j];
    }
    __syncthreads();

    if (t < 64) {
        float acc[8] = {0.f, 0.f, 0.f, 0.f, 0.f, 0.f, 0.f, 0.f};
        #pragma unroll
        for (int w = 0; w < 8; ++w)
            #pragma unroll
            for (int j = 0; j < 8; ++j) acc[j] += partial[w][t][j];

        const int d = t & 15, q = t >> 4;
        float* xplane = xbp + (size_t)zz * 153600;
        float* splane = Sp + (size_t)zz * 4800;
        #pragma unroll
        for (int r = 0; r < 4; ++r) {
            const int row = q * 4 + r;
            const int nn = n0 + row;
            if (nn < 300) {
                float S = 0.f;
                #pragma unroll
                for (int w = 0; w < 8; ++w) S += SrowP[w][row];
                if (d == 0) splane[(size_t)(b * 300 + nn) * 8 + h] = S;
                float* o = xplane + (size_t)(b * 300 + nn) * 256 + h * 32 + d;
                o[0]  = acc[r];
                o[16] = acc[4 + r];
            }
        }
    }
}

// ---------- output projection with fused cross-z combine + 1/S. grid 19 ----------
// In K-step ks all 32 channels belong to head ks, so the softmax normalization
// (1/S) is uniform within the step: A-frag = (sum_z xbp) / (sum_z Sp).
__global__ __launch_bounds__(256) void proj_out(
    const float* __restrict__ xbp, const float* __restrict__ Sp,
    const unsigned short* __restrict__ Wtp,
    const float* __restrict__ bp, float* __restrict__ out)
{
    const int t = threadIdx.x;
    const int wave = t >> 6, lane = t & 63;
    const int m16 = lane & 15, quad = lane >> 4;
    const int msub = (wave & 1) * 16;
    const int nc0 = (wave >> 1) * 128;
    const int m0 = blockIdx.x * 32;

    const int arow = min(m0 + msub + m16, 599);
    const float* a0p = xbp + (size_t)arow * 256 + quad * 8;

    float4v acc[8];
    #pragma unroll
    for (int i = 0; i < 8; ++i) acc[i] = (float4v){0.f, 0.f, 0.f, 0.f};

    #pragma unroll
    for (int ks = 0; ks < 8; ++ks) {
        const float S = Sp[(size_t)arow * 8 + ks]
                      + Sp[4800 + (size_t)arow * 8 + ks]
                      + Sp[9600 + (size_t)arow * 8 + ks];
        const float rS = 1.0f / S;
        float a[8];
        #pragma unroll
        for (int half = 0; half < 2; ++half) {
            const float* p = a0p + ks * 32 + half * 4;
            float4 x0 = *(const float4*)(p);
            float4 x1 = *(const float4*)(p + 153600);
            float4 x2 = *(const float4*)(p + 307200);
            a[half * 4 + 0] = (x0.x + x1.x + x2.x) * rS;
            a[half * 4 + 1] = (x0.y + x1.y + x2.y) * rS;
            a[half * 4 + 2] = (x0.z + x1.z + x2.z) * rS;
            a[half * 4 + 3] = (x0.w + x1.w + x2.w) * rS;
        }
        short8v af;
        #pragma unroll
        for (int j = 0; j < 8; ++j) af[j] = (short)f2bfu_rn(a[j]);
        #pragma unroll
        for (int i = 0; i < 8; ++i) {
            short8v bfr = *(const short8v*)(Wtp + (size_t)(nc0 + i * 16 + m16) * 256 + ks * 32 + quad * 8);
            acc[i] = __builtin_amdgcn_mfma_f32_16x16x32_bf16(af, bfr, acc[i], 0, 0, 0);
        }
    }

    #pragma unroll
    for (int i = 0; i < 8; ++i) {
        const float bv = bp[nc0 + i * 16 + m16];
        #pragma unroll
        for (int r = 0; r < 4; ++r) {
            int m = m0 + msub + quad * 4 + r;
            if (m < 600)
                out[(size_t)m * 256 + nc0 + i * 16 + m16] = acc[i][r] + bv;
        }
    }
}

// ---------- mask branch: folded scalar fields + 8-pixel vector loads. grid (600,2) ----------
__global__ __launch_bounds__(256) void mask_kernel(
    const bf16* __restrict__ attn,
    const float* __restrict__ W1, const float* __restrict__ b1,
    const float* __restrict__ W2, const float* __restrict__ b2,
    const float* __restrict__ W3, const float* __restrict__ b3,
    const float* __restrict__ Wm, const float* __restrict__ bmp,
    float* __restrict__ out)
{
    __shared__ float g2s[1024];
    __shared__ float g3s[256];
    __shared__ float w1s[64], w2s[64], w3s[64];
    __shared__ float b1s[8], b2s[8], b3s[8];
    __shared__ float wms[24];
    __shared__ float bms;

    const int t  = threadIdx.x;
    const int bn = blockIdx.x;
    const int ph = blockIdx.y;             // pixel half: 0 or 1
    const unsigned short* ap = (const unsigned short*)attn + (size_t)bn * 8 * 5376;

    if (t < 64) { w1s[t] = W1[t]; w2s[t] = W2[t]; w3s[t] = W3[t]; }
    if (t < 8)  { b1s[t] = b1[t]; b2s[t] = b2[t]; b3s[t] = b3[t]; }
    if (t < 24) wms[t] = Wm[t];
    if (t == 0) bms = bmp[0];
    __syncthreads();

    {
        const int l2 = t * 4;
        ushort4v u[8];
        #pragma unroll
        for (int hh = 0; hh < 8; ++hh)
            u[hh] = *(const ushort4v*)(ap + hh * 5376 + 4096 + l2);
        #pragma unroll
        for (int pp = 0; pp < 4; ++pp) {
            float g = 0.f;
            #pragma unroll
            for (int hh = 0; hh < 8; ++hh) {
                float s = b2s[hh];
                #pragma unroll
                for (int hp = 0; hp < 8; ++hp) s += bfu2f(u[hp][pp]) * w2s[hp * 8 + hh];
                g += fmaxf(s, 0.f) * wms[8 + hh];
            }
            g2s[l2 + pp] = g;
        }
    }
    if (t < 64) {
        const int l3 = t * 4;
        ushort4v u[8];
        #pragma unroll
        for (int hh = 0; hh < 8; ++hh)
            u[hh] = *(const ushort4v*)(ap + hh * 5376 + 5120 + l3);
        #pragma unroll
        for (int pp = 0; pp < 4; ++pp) {
            float g = 0.f;
            #pragma unroll
            for (int hh = 0; hh < 8; ++hh) {
                float s = b3s[hh];
                #pragma unroll
                for (int hp = 0; hp < 8; ++hp) s += bfu2f(u[hp][pp]) * w3s[hp * 8 + hh];
                g += fmaxf(s, 0.f) * wms[16 + hh];
            }
            g3s[l3 + pp] = g;
        }
    }
    __syncthreads();

    {
        const int p0 = ph * 2048 + t * 8;
        ushort8v u[8];
        #pragma unroll
        for (int hh = 0; hh < 8; ++hh)
            u[hh] = *(const ushort8v*)(ap + hh * 5376 + p0);

        float res[8];
        #pragma unroll
        for (int pp = 0; pp < 8; ++pp) {
            const int p = p0 + pp;
            const int Y = p >> 6, X = p & 63;

            float acc = bms;
            #pragma unroll
            for (int hh = 0; hh < 8; ++hh) {
                float s = b1s[hh];
                #pragma unroll
                for (int hp = 0; hp < 8; ++hp) s += bfu2f(u[hp][pp]) * w1s[hp * 8 + hh];
                acc += fmaxf(s, 0.f) * wms[hh];
            }
            {
                float ry = fminf(fmaxf(0.5f * Y - 0.25f, 0.f), 31.f);
                float rx = fminf(fmaxf(0.5f * X - 0.25f, 0.f), 31.f);
                int y0 = (int)ry, x0 = (int)rx;
                int y1 = min(y0 + 1, 31), x1 = min(x0 + 1, 31);
                float wy = ry - (float)y0, wx = rx - (float)x0;
                acc += (g2s[y0 * 32 + x0] * (1.f - wx) + g2s[y0 * 32 + x1] * wx) * (1.f - wy)
                     + (g2s[y1 * 32 + x0] * (1.f - wx) + g2s[y1 * 32 + x1] * wx) * wy;
            }
            {
                float ry = fminf(fmaxf(0.25f * Y - 0.375f, 0.f), 15.f);
                float rx = fminf(fmaxf(0.25f * X - 0.375f, 0.f), 15.f);
                int y0 = (int)ry, x0 = (int)rx;
                int y1 = min(y0 + 1, 15), x1 = min(x0 + 1, 15);
                float wy = ry - (float)y0, wx = rx - (float)x0;
                acc += (g3s[y0 * 16 + x0] * (1.f - wx) + g3s[y0 * 16 + x1] * wx) * (1.f - wy)
                     + (g3s[y1 * 16 + x0] * (1.f - wx) + g3s[y1 * 16 + x1] * wx) * wy;
            }
            res[pp] = fmaxf(acc, 0.f);
        }
        float* o = out + 153600 + (size_t)bn * 4096 + p0;
        #pragma unroll
        for (int pp = 0; pp < 8; ++pp) o[pp] = res[pp];
    }
}

// ---------- launch ----------
extern "C" void kernel_launch(void* const* d_in, const int* in_sizes, int n_in,
                              void* d_out, int out_size, void* d_ws, size_t ws_size,
                              hipStream_t stream) {
    const float* query = (const float*)d_in[0];
    const float* key   = (const float*)d_in[1];
    const float* value = (const float*)d_in[2];
    const float* Wq = (const float*)d_in[5];
    const float* Wk = (const float*)d_in[6];
    const float* Wv = (const float*)d_in[7];
    const float* Wp = (const float*)d_in[8];
    const float* bp = (const float*)d_in[9];
    const float* W1 = (const float*)d_in[10];
    const float* b1 = (const float*)d_in[11];
    const float* W2 = (const float*)d_in[12];
    const float* b2 = (const float*)d_in[13];
    const float* W3 = (const float*)d_in[14];
    const float* b3 = (const float*)d_in[15];
    const float* Wm = (const float*)d_in[16];
    const float* bm = (const float*)d_in[17];
    float* out = (float*)d_out;

    char* ws = (char*)d_ws;
    unsigned short* wt = (unsigned short*)(ws);       // 4*65536 bf16 = 524,288 B
    bf16*  qb   = (bf16*) (ws + 524288);              // 600*256 bf16
    bf16*  kb   = (bf16*) (ws + 831488);              // 10752*256 bf16
    bf16*  vt   = (bf16*) (ws + 6336512);             // 512*5376 bf16
    bf16*  attn = (bf16*) (ws + 11841536);            // 600*8*5376 bf16
    float* xbp  = (float*)(ws + 63451136);            // 3*600*256 fp32 = 1,843,200 B
    float* Sp   = (float*)(ws + 65294336);            // 3*4800 fp32    =    57,600 B

    cast_wt<<<dim3(4, 4, 4), 256, 0, stream>>>(Wq, Wk, Wv, Wp, wt);

    proj_all<<<691, 256, 0, stream>>>(query, key, value, wt,
        (unsigned short*)qb, (unsigned short*)kb, (unsigned short*)vt);

    attn_fused<<<dim3(19, 16, 3), 512, 0, stream>>>(
        (const unsigned short*)qb, (const unsigned short*)kb, (const unsigned short*)vt,
        (unsigned short*)attn, xbp, Sp);

    mask_kernel<<<dim3(600, 2), 256, 0, stream>>>(attn, W1, b1, W2, b2, W3, b3, Wm, bm, out);

    proj_out<<<19, 256, 0, stream>>>(xbp, Sp, (const unsigned short*)wt + 196608, bp, out);
}